// Round 1
// baseline (4256.021 us; speedup 1.0000x reference)
//
#include <hip/hip_runtime.h>

#define SEQ 64

__device__ __forceinline__ float sig_(float x) { return 1.0f / (1.0f + __expf(-x)); }
__device__ __forceinline__ float tanh_(float x) { return 1.0f - 2.0f / (1.0f + __expf(2.0f * x)); }

// hT layout: row = feature k in [0,128), col = node n in [0,64), XOR-swizzled in 4-blocks
__device__ __forceinline__ int swz(int row, int n) {
  return row * 64 + ((((n >> 2) ^ (row & 15)) << 2) | (n & 3));
}

template<int NQ>
__device__ __forceinline__ void phase1_gemm(
    int d, int g, int W,
    const float* __restrict__ cW, const float* __restrict__ cb,
    const float* __restrict__ selw,
    const float* hT, const float* stc,
    float* comp_h, float* comp_c, float* part_)
{
  float acc[5][NQ * 4];
  #pragma unroll
  for (int q = 0; q < 5; ++q)
    #pragma unroll
    for (int j = 0; j < NQ * 4; ++j) acc[q][j] = 0.f;

  const int n0 = g * 16;
  for (int k = 0; k < 128; ++k) {
    const float* wl = cW + k * 640 + d;            // left-half weight row k
    const float* wr = cW + (128 + k) * 640 + d;    // right-half weight row 128+k
    float wlq[5], wrq[5];
    #pragma unroll
    for (int q = 0; q < 5; ++q) { wlq[q] = wl[q * 128]; wrq[q] = wr[q * 128]; }

    float hv[NQ * 4 + 1];
    #pragma unroll
    for (int m = 0; m < NQ; ++m) {
      const float4 t = *(const float4*)&hT[k * 64 + (((g * 4 + m) ^ (k & 15)) << 2)];
      hv[m * 4 + 0] = t.x; hv[m * 4 + 1] = t.y; hv[m * 4 + 2] = t.z; hv[m * 4 + 3] = t.w;
    }
    {
      const int nn = n0 + NQ * 4;                  // extra node for right-shift
      hv[NQ * 4] = (nn < 64) ? hT[swz(k, nn)] : 0.f;
    }
    #pragma unroll
    for (int j = 0; j < NQ * 4; ++j) {
      const float hl = hv[j], hr = hv[j + 1];
      #pragma unroll
      for (int q = 0; q < 5; ++q)
        acc[q][j] = __builtin_fmaf(hr, wrq[q], __builtin_fmaf(hl, wlq[q], acc[q][j]));
    }
  }

  float bq[5];
  #pragma unroll
  for (int q = 0; q < 5; ++q) bq[q] = cb[q * 128 + d];
  const float swh = selw[d], swc = selw[128 + d];
  #pragma unroll
  for (int j = 0; j < NQ * 4; ++j) {
    const int n = n0 + j;
    if (n < W) {                                   // wave-uniform guard
      const float iv = acc[0][j] + bq[0];
      const float fl = acc[1][j] + bq[1];
      const float fr = acc[2][j] + bq[2];
      const float gv = acc[3][j] + bq[3];
      const float ov = acc[4][j] + bq[4];
      const float cl = stc[n * 128 + d];
      const float cr = stc[(n + 1) * 128 + d];
      const float c  = sig_(fl) * cl + sig_(fr) * cr + sig_(iv) * tanh_(gv);
      const float h  = sig_(ov) * tanh_(c);
      comp_h[j] = h; comp_c[j] = c;
      part_[j]  = h * swh + c * swc;               // logit partial for feature d
    }
  }
}

__global__ __launch_bounds__(512, 2) void pyramid_kernel(
    const int*   __restrict__ sentences,
    const float* __restrict__ emb,
    const float* __restrict__ cW,   const float* __restrict__ cb,
    const float* __restrict__ selw, const float* __restrict__ selb,
    const float* __restrict__ w0,   const float* __restrict__ b0,
    const float* __restrict__ w1,   const float* __restrict__ b1,
    const float* __restrict__ cwt,  const float* __restrict__ cbias,
    float* __restrict__ out, float* __restrict__ ws)
{
  __shared__ __align__(16) float hT[128 * 64];   // h half, transposed+swizzled (32KB)
  __shared__ __align__(16) float stc[64 * 128];  // c half, natural layout      (32KB)

  const int tid  = threadIdx.x;
  const int b    = blockIdx.x;
  const int d    = tid & 127;   // feature within half
  const int g    = tid >> 7;    // node chunk (16 nodes each)
  const int wv   = tid >> 6;    // wave id
  const int lane = tid & 63;
  volatile float* lp = ws + (size_t)b * 256;     // per-block logit-partial scratch

  // ---------------- embedding gather ----------------
  {
    const int s    = tid >> 3;
    const int part = tid & 7;
    const int row  = sentences[b * SEQ + s];
    const float4* er = (const float4*)(emb + (size_t)row * 256 + part * 32);
    #pragma unroll
    for (int i4 = 0; i4 < 8; ++i4) {
      const float4 v = er[i4];
      const float vv[4] = {v.x, v.y, v.z, v.w};
      #pragma unroll
      for (int c = 0; c < 4; ++c) {
        const int f = part * 32 + i4 * 4 + c;
        if (f < 128) hT[swz(f, s)] = vv[c];
        else         stc[s * 128 + (f - 128)] = vv[c];
      }
    }
  }
  __syncthreads();

  const float selbv = selb[0];
  float comp_h[16], comp_c[16];

  // ---------------- pyramid: 63 layers ----------------
  for (int L = SEQ; L >= 2; --L) {
    const int W  = L - 1;
    const int n0 = g * 16;
    const int jn = W - n0;

    float part_[16];
    #pragma unroll
    for (int j = 0; j < 16; ++j) { comp_h[j] = 0.f; comp_c[j] = 0.f; part_[j] = 0.f; }

    if (jn > 0) {
      if (jn >= 13)      phase1_gemm<4>(d, g, W, cW, cb, selw, hT, stc, comp_h, comp_c, part_);
      else if (jn >= 9)  phase1_gemm<3>(d, g, W, cW, cb, selw, hT, stc, comp_h, comp_c, part_);
      else if (jn >= 5)  phase1_gemm<2>(d, g, W, cW, cb, selw, hT, stc, comp_h, comp_c, part_);
      else               phase1_gemm<1>(d, g, W, cW, cb, selw, hT, stc, comp_h, comp_c, part_);

      // reduce logit partials over the 64 lanes (features) of this wave
      #pragma unroll
      for (int j = 0; j < 16; ++j) {
        float v = part_[j];
        #pragma unroll
        for (int s = 1; s < 64; s <<= 1) v += __shfl_xor(v, s, 64);
        part_[j] = v;
      }
      if (lane == 0) {
        const int half = wv & 1;
        #pragma unroll
        for (int j = 0; j < 16; ++j) {
          const int n = n0 + j;
          if (n < W) lp[half * 64 + n] = part_[j];
        }
      }
    }
    __threadfence_block();
    __syncthreads();

    // ---- phase 2: softmax + prefix sums (redundantly per wave, in registers) ----
    float p_r, cl_r, cr_r;
    {
      float lg = -3.0e38f;
      if (lane < W) lg = lp[lane] + lp[64 + lane] + selbv;
      float m = lg;
      #pragma unroll
      for (int s = 32; s >= 1; s >>= 1) m = fmaxf(m, __shfl_xor(m, s, 64));
      const float e = (lane < W) ? __expf(lg - m) : 0.f;
      float t = e;
      #pragma unroll
      for (int s = 32; s >= 1; s >>= 1) t += __shfl_xor(t, s, 64);
      const float p = e / t;
      float cs = p;
      #pragma unroll
      for (int off = 1; off < 64; off <<= 1) {
        const float v = __shfl_up(cs, off, 64);
        if (lane >= off) cs += v;
      }
      const float T = __shfl(cs, 63, 64);
      p_r = p; cl_r = T - cs; cr_r = cs - p;   // copy_left, copy_right
    }

    // ---- phase 3a: blend into registers ----
    float nh[16], nc[16];
    float hv2[17];
    #pragma unroll
    for (int m = 0; m < 4; ++m) {
      const float4 t = *(const float4*)&hT[d * 64 + (((g * 4 + m) ^ (d & 15)) << 2)];
      hv2[m * 4 + 0] = t.x; hv2[m * 4 + 1] = t.y; hv2[m * 4 + 2] = t.z; hv2[m * 4 + 3] = t.w;
    }
    hv2[16] = (n0 + 16 < 64) ? hT[swz(d, n0 + 16)] : 0.f;
    #pragma unroll
    for (int j = 0; j < 16; ++j) {
      const int n = n0 + j;
      if (n < W) {
        const float p  = __shfl(p_r,  n, 64);
        const float cl = __shfl(cl_r, n, 64);
        const float cr = __shfl(cr_r, n, 64);
        const float lc = stc[n * 128 + d];
        const float rc = stc[(n + 1) * 128 + d];
        nh[j] = cl * hv2[j] + cr * hv2[j + 1] + p * comp_h[j];
        nc[j] = cl * lc + cr * rc + p * comp_c[j];
      } else { nh[j] = 0.f; nc[j] = 0.f; }
    }
    __syncthreads();
    // ---- phase 3b: write back ----
    #pragma unroll
    for (int m = 0; m < 4; ++m) {
      const int n = n0 + m * 4;
      if (n + 3 < W) {
        float4 t; t.x = nh[m*4]; t.y = nh[m*4+1]; t.z = nh[m*4+2]; t.w = nh[m*4+3];
        *(float4*)&hT[d * 64 + (((g * 4 + m) ^ (d & 15)) << 2)] = t;
      } else {
        #pragma unroll
        for (int c = 0; c < 4; ++c)
          if (n + c < W) hT[swz(d, n + c)] = nh[m * 4 + c];
      }
    }
    #pragma unroll
    for (int j = 0; j < 16; ++j) {
      const int n = n0 + j;
      if (n < W) stc[n * 128 + d] = nc[j];
    }
    __syncthreads();
  }

  // ---------------- MLP head on states[:,0] ----------------
  float z0a = b0[tid], z0b = b0[tid + 512];
  for (int k = 0; k < 128; ++k) {
    const float hk = hT[k * 64 + ((k & 15) << 2)];   // hT[k][0]
    z0a = __builtin_fmaf(hk, w0[k * 1024 + tid], z0a);
    z0b = __builtin_fmaf(hk, w0[k * 1024 + tid + 512], z0b);
  }
  for (int k = 0; k < 128; ++k) {
    const float ck = stc[k];                          // stc[0][k]
    z0a = __builtin_fmaf(ck, w0[(128 + k) * 1024 + tid], z0a);
    z0b = __builtin_fmaf(ck, w0[(128 + k) * 1024 + tid + 512], z0b);
  }
  z0a = fmaxf(z0a, 0.f); z0b = fmaxf(z0b, 0.f);
  __syncthreads();
  stc[tid] = z0a; stc[512 + tid] = z0b;               // z0 -> stc[0..1023]
  __syncthreads();
  float z1a = b1[tid], z1b = b1[tid + 512];
  for (int k = 0; k < 1024; ++k) {
    const float zk = stc[k];
    z1a = __builtin_fmaf(zk, w1[k * 1024 + tid], z1a);
    z1b = __builtin_fmaf(zk, w1[k * 1024 + tid + 512], z1b);
  }
  z1a = fmaxf(z1a, 0.f); z1b = fmaxf(z1b, 0.f);
  __syncthreads();
  hT[tid] = z1a; hT[512 + tid] = z1b;                 // z1 -> hT[0..1023]
  __syncthreads();
  if (wv < 3) {
    float s = 0.f;
    #pragma unroll
    for (int i = 0; i < 16; ++i) {
      const int k = lane + i * 64;
      s = __builtin_fmaf(hT[k], cwt[k * 3 + wv], s);
    }
    #pragma unroll
    for (int off = 32; off >= 1; off >>= 1) s += __shfl_xor(s, off, 64);
    if (lane == 0) out[b * 3 + wv] = s + cbias[wv];
  }
}

extern "C" void kernel_launch(void* const* d_in, const int* in_sizes, int n_in,
                              void* d_out, int out_size, void* d_ws, size_t ws_size,
                              hipStream_t stream) {
  (void)in_sizes; (void)n_in; (void)out_size; (void)ws_size;
  pyramid_kernel<<<dim3(64), dim3(512), 0, stream>>>(
      (const int*)d_in[0],          // sentences
      (const float*)d_in[2],        // emb
      (const float*)d_in[3],        // comp_W
      (const float*)d_in[4],        // comp_b
      (const float*)d_in[5],        // sel_w
      (const float*)d_in[6],        // sel_b
      (const float*)d_in[7],        // mlp_w0
      (const float*)d_in[8],        // mlp_b0
      (const float*)d_in[9],        // mlp_w1
      (const float*)d_in[10],       // mlp_b1
      (const float*)d_in[11],       // cls_w
      (const float*)d_in[12],       // cls_b
      (float*)d_out, (float*)d_ws);
}

// Round 2
// 947.839 us; speedup vs baseline: 4.4902x; 4.4902x over previous
//
#include <hip/hip_runtime.h>

#define SEQ 64

typedef _Float16 f16;
typedef _Float16 f16x8 __attribute__((ext_vector_type(8)));
typedef float f32x4 __attribute__((ext_vector_type(4)));

__device__ __forceinline__ float sig_(float x) { return 1.0f / (1.0f + __expf(-x)); }
__device__ __forceinline__ float tanh_(float x) { return 1.0f - 2.0f / (1.0f + __expf(2.0f * x)); }

// h state: node-major, 128 f16/row, XOR-swizzled in 8-f16 (16B) blocks
__device__ __forceinline__ int hOff(int n, int f) {
  return n * 128 + ((((f >> 3) ^ (n & 15)) << 3) | (f & 7));
}

// ---- prep: comp_W (256x640 fp32) -> f16 MFMA B-fragment order in ws ----
// frag idx (kk,nt): lane holds B[k=kk*32+quad*8+j][n=nt*16+(lane&15)]
__global__ void prep_kernel(const float* __restrict__ cW, f16* __restrict__ wsB) {
  const int idx  = blockIdx.x * 256 + threadIdx.x;   // 0..20479
  const int kk   = idx / 2560;
  const int rem  = idx - kk * 2560;
  const int nt   = rem >> 6;
  const int lane = rem & 63;
  const int col  = nt * 16 + (lane & 15);
  const int kb   = kk * 32 + ((lane >> 4) << 3);
  f16x8 v;
  #pragma unroll
  for (int j = 0; j < 8; ++j) v[j] = (f16)cW[(kb + j) * 640 + col];
  ((f16x8*)wsB)[idx] = v;
}

template<int NMT>
__device__ __forceinline__ void layer_step(
    const int W, const int wv, const int lane, const int quad, const int l15, const int d,
    const float* bq, const float swh, const float swc, const float selbv,
    const f16x8* __restrict__ Bf, f16* hS, float* cS, float* lgp)
{
  // ---- phase A: MFMA GEMM, comp = [h_l||h_r] @ comp_W ----
  f32x4 acc[NMT][5];
  #pragma unroll
  for (int mt = 0; mt < NMT; ++mt)
    #pragma unroll
    for (int q = 0; q < 5; ++q) acc[mt][q] = (f32x4){0.f, 0.f, 0.f, 0.f};

  #pragma unroll
  for (int kk = 0; kk < 8; ++kk) {
    const int na  = kk >> 2;              // right half reads node n+1
    const int blk = (kk & 3) * 4 + quad;
    f16x8 av[NMT];
    #pragma unroll
    for (int mt = 0; mt < NMT; ++mt) {
      const int n = mt * 16 + l15 + na;
      av[mt] = *(const f16x8*)&hS[n * 128 + ((blk ^ (n & 15)) << 3)];
    }
    #pragma unroll
    for (int q = 0; q < 5; ++q) {
      const f16x8 bv = Bf[((kk * 40 + q * 8 + wv) << 6) + lane];
      #pragma unroll
      for (int mt = 0; mt < NMT; ++mt)
        acc[mt][q] = __builtin_amdgcn_mfma_f32_16x16x32_f16(av[mt], bv, acc[mt][q], 0, 0, 0);
    }
  }

  // ---- epilogue: gates (C-layout: d=lane&15 col, n=quad*4+r row) ----
  float ch[NMT][4], cc[NMT][4];
  #pragma unroll
  for (int mt = 0; mt < NMT; ++mt) {
    float pl[4];
    #pragma unroll
    for (int r = 0; r < 4; ++r) {
      const int n = mt * 16 + quad * 4 + r;
      const float ocl = cS[n * 132 + d];
      const float ocr = cS[(n + 1) * 132 + d];
      const float iv = acc[mt][0][r] + bq[0];
      const float fl = acc[mt][1][r] + bq[1];
      const float fr = acc[mt][2][r] + bq[2];
      const float gv = acc[mt][3][r] + bq[3];
      const float ov = acc[mt][4][r] + bq[4];
      const float c = sig_(fl) * ocl + sig_(fr) * ocr + sig_(iv) * tanh_(gv);
      const float h = sig_(ov) * tanh_(c);
      cc[mt][r] = c; ch[mt][r] = h;
      pl[r] = __builtin_fmaf(h, swh, c * swc);
    }
    #pragma unroll
    for (int r = 0; r < 4; ++r) {           // reduce logit partial over 16 d of this wave
      float v = pl[r];
      v += __shfl_xor(v, 1, 64); v += __shfl_xor(v, 2, 64);
      v += __shfl_xor(v, 4, 64); v += __shfl_xor(v, 8, 64);
      pl[r] = v;
    }
    if (l15 == 0) {
      #pragma unroll
      for (int r = 0; r < 4; ++r) {
        const int n = mt * 16 + quad * 4 + r;
        if (n < W) lgp[(wv << 6) + n] = pl[r];
      }
    }
  }
  __syncthreads();

  // ---- phase B: softmax + prefix sums, redundantly per wave ----
  float p_r, clw_r, crw_r;
  {
    float lg = -3.0e38f;
    if (lane < W) {
      float s = lgp[lane];
      #pragma unroll
      for (int dg = 1; dg < 8; ++dg) s += lgp[(dg << 6) + lane];
      lg = s + selbv;
    }
    float m = lg;
    #pragma unroll
    for (int s = 32; s >= 1; s >>= 1) m = fmaxf(m, __shfl_xor(m, s, 64));
    const float e = (lane < W) ? __expf(lg - m) : 0.f;
    float t = e;
    #pragma unroll
    for (int s = 32; s >= 1; s >>= 1) t += __shfl_xor(t, s, 64);
    const float p = e / t;
    float cs = p;
    #pragma unroll
    for (int off = 1; off < 64; off <<= 1) {
      const float v = __shfl_up(cs, off, 64);
      if (lane >= off) cs += v;
    }
    const float T = __shfl(cs, 63, 64);
    p_r = p; clw_r = T - cs; crw_r = cs - p;  // copy_left, copy_right
  }

  // ---- phase C pass 1: blend into registers (reads only; own d-columns) ----
  #pragma unroll
  for (int mt = 0; mt < NMT; ++mt) {
    #pragma unroll
    for (int r = 0; r < 4; ++r) {
      const int n = mt * 16 + quad * 4 + r;
      const float pw  = __shfl(p_r,   n, 64);
      const float clw = __shfl(clw_r, n, 64);
      const float crw = __shfl(crw_r, n, 64);
      const float ohl = (float)hS[hOff(n, d)];
      const float ohr = (float)hS[hOff(n + 1, d)];
      const float ocl = cS[n * 132 + d];
      const float ocr = cS[(n + 1) * 132 + d];
      ch[mt][r] = clw * ohl + crw * ohr + pw * ch[mt][r];
      cc[mt][r] = clw * ocl + crw * ocr + pw * cc[mt][r];
    }
  }
  // ---- phase C pass 2: write back ----
  #pragma unroll
  for (int mt = 0; mt < NMT; ++mt)
    #pragma unroll
    for (int r = 0; r < 4; ++r) {
      const int n = mt * 16 + quad * 4 + r;
      if (n < W) {
        hS[hOff(n, d)] = (f16)ch[mt][r];
        cS[n * 132 + d] = cc[mt][r];
      }
    }
  __syncthreads();
}

__global__ __launch_bounds__(512, 2) void pyramid_kernel(
    const int*   __restrict__ sentences,
    const float* __restrict__ emb,
    const f16*   __restrict__ wsB,
    const float* __restrict__ cb,   const float* __restrict__ selw, const float* __restrict__ selb,
    const float* __restrict__ w0,   const float* __restrict__ b0,
    const float* __restrict__ w1,   const float* __restrict__ b1,
    const float* __restrict__ cwt,  const float* __restrict__ cbias,
    float* __restrict__ out)
{
  __shared__ __align__(16) f16   hS[65 * 128];   // h, f16 swizzled (16.6 KB)
  __shared__ __align__(16) float cS[65 * 132];   // c, f32 padded   (34.3 KB)
  __shared__ float lgp[8 * 64];                  // logit partials  (2 KB)

  const int tid  = threadIdx.x;
  const int b    = blockIdx.x;
  const int wv   = tid >> 6;       // wave = d-group (16 cols of each gate)
  const int lane = tid & 63;
  const int quad = lane >> 4;
  const int l15  = lane & 15;
  const int d    = wv * 16 + l15;  // feature column within half

  // ---- embedding gather ----
  {
    const int s = tid >> 3, part = tid & 7;
    const int row = sentences[b * SEQ + s];
    const float4* er = (const float4*)(emb + (size_t)row * 256 + part * 32);
    #pragma unroll
    for (int i4 = 0; i4 < 8; ++i4) {
      const float4 v = er[i4];
      const float vv[4] = {v.x, v.y, v.z, v.w};
      #pragma unroll
      for (int c = 0; c < 4; ++c) {
        const int f = part * 32 + i4 * 4 + c;
        if (f < 128) hS[hOff(s, f)] = (f16)vv[c];
        else         cS[s * 132 + (f - 128)] = vv[c];
      }
    }
  }
  if (tid < 128) hS[64 * 128 + tid] = (f16)0.f;   // guard row (node 64)
  if (tid < 132) cS[64 * 132 + tid] = 0.f;
  __syncthreads();

  float bq[5];
  #pragma unroll
  for (int q = 0; q < 5; ++q) bq[q] = cb[q * 128 + d];
  const float swh = selw[d], swc = selw[128 + d], selbv = selb[0];
  const f16x8* Bf = (const f16x8*)wsB;

  // ---- pyramid: 63 sequential layers ----
  for (int W = 63; W >= 1; --W) {
    switch ((W + 15) >> 4) {
      case 4: layer_step<4>(W, wv, lane, quad, l15, d, bq, swh, swc, selbv, Bf, hS, cS, lgp); break;
      case 3: layer_step<3>(W, wv, lane, quad, l15, d, bq, swh, swc, selbv, Bf, hS, cS, lgp); break;
      case 2: layer_step<2>(W, wv, lane, quad, l15, d, bq, swh, swc, selbv, Bf, hS, cS, lgp); break;
      default: layer_step<1>(W, wv, lane, quad, l15, d, bq, swh, swc, selbv, Bf, hS, cS, lgp); break;
    }
  }

  // ---- MLP head on state[0] = [h0 || c0] ----
  {
    float z0a = b0[2 * tid], z0b = b0[2 * tid + 1];
    #pragma unroll 4
    for (int k = 0; k < 256; ++k) {
      const float xk = (k < 128) ? (float)hS[k] : cS[k - 128];  // hOff(0,f)=f
      const float2 w = *(const float2*)&w0[k * 1024 + 2 * tid];
      z0a = __builtin_fmaf(xk, w.x, z0a);
      z0b = __builtin_fmaf(xk, w.y, z0b);
    }
    z0a = fmaxf(z0a, 0.f); z0b = fmaxf(z0b, 0.f);
    float* zbuf = &cS[264];                       // disjoint from cS[0..127]
    zbuf[2 * tid] = z0a; zbuf[2 * tid + 1] = z0b;
    __syncthreads();

    float z1a = b1[2 * tid], z1b = b1[2 * tid + 1];
    #pragma unroll 4
    for (int k = 0; k < 1024; ++k) {
      const float zk = zbuf[k];
      const float2 w = *(const float2*)&w1[k * 1024 + 2 * tid];
      z1a = __builtin_fmaf(zk, w.x, z1a);
      z1b = __builtin_fmaf(zk, w.y, z1b);
    }
    z1a = fmaxf(z1a, 0.f); z1b = fmaxf(z1b, 0.f);
    float* z1buf = &cS[264 + 1024];
    z1buf[2 * tid] = z1a; z1buf[2 * tid + 1] = z1b;
    __syncthreads();

    if (wv < 3) {
      float s = 0.f;
      #pragma unroll
      for (int i = 0; i < 16; ++i) {
        const int k = lane + (i << 6);
        s = __builtin_fmaf(z1buf[k], cwt[k * 3 + wv], s);
      }
      #pragma unroll
      for (int off = 32; off >= 1; off >>= 1) s += __shfl_xor(s, off, 64);
      if (lane == 0) out[b * 3 + wv] = s + cbias[wv];
    }
  }
}

extern "C" void kernel_launch(void* const* d_in, const int* in_sizes, int n_in,
                              void* d_out, int out_size, void* d_ws, size_t ws_size,
                              hipStream_t stream) {
  (void)in_sizes; (void)n_in; (void)out_size; (void)ws_size;
  prep_kernel<<<dim3(80), dim3(256), 0, stream>>>((const float*)d_in[3], (f16*)d_ws);
  pyramid_kernel<<<dim3(64), dim3(512), 0, stream>>>(
      (const int*)d_in[0],          // sentences
      (const float*)d_in[2],        // emb
      (const f16*)d_ws,             // comp_W, f16 B-fragment order
      (const float*)d_in[4],        // comp_b
      (const float*)d_in[5],        // sel_w
      (const float*)d_in[6],        // sel_b
      (const float*)d_in[7],        // mlp_w0
      (const float*)d_in[8],        // mlp_b0
      (const float*)d_in[9],        // mlp_w1
      (const float*)d_in[10],       // mlp_b1
      (const float*)d_in[11],       // cls_w
      (const float*)d_in[12],       // cls_b
      (float*)d_out);
}

// Round 3
// 897.811 us; speedup vs baseline: 4.7404x; 1.0557x over previous
//
#include <hip/hip_runtime.h>

#define SEQ 64

typedef _Float16 f16;
typedef _Float16 f16x8 __attribute__((ext_vector_type(8)));
typedef float f32x4 __attribute__((ext_vector_type(4)));

__device__ __forceinline__ float sig_(float x) { return 1.0f / (1.0f + __expf(-x)); }
__device__ __forceinline__ float tanh_(float x) { return 1.0f - 2.0f / (1.0f + __expf(2.0f * x)); }

// DPP helpers (VALU-pipe cross-lane, no LDS traffic)
template<int CTRL, int RMASK>
__device__ __forceinline__ float dpp_add(float x) {
  const int t = __builtin_amdgcn_update_dpp(0, __float_as_int(x), CTRL, RMASK, 0xF, true);
  return x + __int_as_float(t);
}
template<int CTRL>
__device__ __forceinline__ float dpp_max(float x) {
  const int t = __builtin_amdgcn_update_dpp(0, __float_as_int(x), CTRL, 0xF, 0xF, true);
  return fmaxf(x, __int_as_float(t));
}

// h state: node-major, 128 f16/row, XOR-swizzled in 8-f16 (16B) blocks
__device__ __forceinline__ int hOff(int n, int f) {
  return n * 128 + ((((f >> 3) ^ (n & 15)) << 3) | (f & 7));
}

// ---- prep: comp_W (256x640 fp32) -> f16 MFMA B-fragment order in ws ----
__global__ void prep_kernel(const float* __restrict__ cW, f16* __restrict__ wsB) {
  const int idx  = blockIdx.x * 256 + threadIdx.x;   // 0..20479
  const int kk   = idx / 2560;
  const int rem  = idx - kk * 2560;
  const int nt   = rem >> 6;
  const int lane = rem & 63;
  const int col  = nt * 16 + (lane & 15);
  const int kb   = kk * 32 + ((lane >> 4) << 3);
  f16x8 v;
  #pragma unroll
  for (int j = 0; j < 8; ++j) v[j] = (f16)cW[(kb + j) * 640 + col];
  ((f16x8*)wsB)[idx] = v;
}

__global__ __launch_bounds__(512, 2) void pyramid_kernel(
    const int*   __restrict__ sentences,
    const float* __restrict__ emb,
    const f16*   __restrict__ wsB,
    const float* __restrict__ cb, const float* __restrict__ selw, const float* __restrict__ selb,
    float* __restrict__ fin)
{
  __shared__ __align__(16) f16   hS[65 * 128];   // h, f16 swizzled (16.6 KB)
  __shared__ __align__(16) float cS[65 * 132];   // c, f32 padded   (34.3 KB)
  __shared__ float lgp[8 * 64];                  // logit partials  (2 KB)
  __shared__ __align__(16) float pS[64], clS[64], crS[64];

  const int tid  = threadIdx.x;
  const int b    = blockIdx.x;
  const int wv   = tid >> 6;       // wave = d-group (16 cols of each gate)
  const int lane = tid & 63;
  const int quad = lane >> 4;
  const int l15  = lane & 15;
  const int d    = wv * 16 + l15;

  // ---- persistent B fragments: 40 x f16x8 = 160 VGPRs, loaded ONCE ----
  f16x8 Breg[8][5];
  {
    const f16x8* Bf = (const f16x8*)wsB;
    #pragma unroll
    for (int kk = 0; kk < 8; ++kk)
      #pragma unroll
      for (int q = 0; q < 5; ++q)
        Breg[kk][q] = Bf[((kk * 40 + q * 8 + wv) << 6) + lane];
  }

  // ---- embedding gather ----
  {
    const int s = tid >> 3, part = tid & 7;
    const int row = sentences[b * SEQ + s];
    const float4* er = (const float4*)(emb + (size_t)row * 256 + part * 32);
    #pragma unroll
    for (int i4 = 0; i4 < 8; ++i4) {
      const float4 v = er[i4];
      const float vv[4] = {v.x, v.y, v.z, v.w};
      #pragma unroll
      for (int c = 0; c < 4; ++c) {
        const int f = part * 32 + i4 * 4 + c;
        if (f < 128) hS[hOff(s, f)] = (f16)vv[c];
        else         cS[s * 132 + (f - 128)] = vv[c];
      }
    }
  }
  if (tid < 128) hS[64 * 128 + tid] = (f16)0.f;   // guard row (node 64)
  if (tid < 132) cS[64 * 132 + tid] = 0.f;
  __syncthreads();

  float bq[5];
  #pragma unroll
  for (int q = 0; q < 5; ++q) bq[q] = cb[q * 128 + d];
  const float swh = selw[d], swc = selw[128 + d], selbv = selb[0];

  // ---- pyramid: 63 sequential layers, NO global memory in the loop ----
  for (int W = 63; W >= 1; --W) {
    const int NMT = (W + 15) >> 4;
    float ch[4][4], cc[4][4];

    // ---- phase A: MFMA GEMM + gate epilogue, one M-tile at a time ----
    #pragma unroll
    for (int mt = 0; mt < 4; ++mt) if (mt < NMT) {
      f32x4 acc[5];
      #pragma unroll
      for (int q = 0; q < 5; ++q) acc[q] = (f32x4){bq[q], bq[q], bq[q], bq[q]};
      #pragma unroll
      for (int kk = 0; kk < 8; ++kk) {
        const int n   = mt * 16 + l15 + (kk >> 2);   // right-half h reads node n+1
        const int blk = (kk & 3) * 4 + quad;
        const f16x8 av = *(const f16x8*)&hS[n * 128 + ((blk ^ (n & 15)) << 3)];
        #pragma unroll
        for (int q = 0; q < 5; ++q)
          acc[q] = __builtin_amdgcn_mfma_f32_16x16x32_f16(av, Breg[kk][q], acc[q], 0, 0, 0);
      }
      const int n0q = mt * 16 + quad * 4;
      float pl[4];
      #pragma unroll
      for (int r = 0; r < 4; ++r) {
        const int n = n0q + r;
        const float ocl = cS[n * 132 + d];
        const float ocr = cS[(n + 1) * 132 + d];
        const float c = sig_(acc[1][r]) * ocl + sig_(acc[2][r]) * ocr + sig_(acc[0][r]) * tanh_(acc[3][r]);
        const float h = sig_(acc[4][r]) * tanh_(c);
        cc[mt][r] = c; ch[mt][r] = h;
        pl[r] = __builtin_fmaf(h, swh, c * swc);
      }
      // reduce pl over the 16 lanes (l15) via DPP: xor1, xor2, ror4, ror8
      #pragma unroll
      for (int r = 0; r < 4; ++r) {
        float v = pl[r];
        v = dpp_add<0xB1, 0xF>(v);
        v = dpp_add<0x4E, 0xF>(v);
        v = dpp_add<0x124, 0xF>(v);
        v = dpp_add<0x128, 0xF>(v);
        pl[r] = v;
      }
      if (l15 == 0) {
        #pragma unroll
        for (int r = 0; r < 4; ++r)
          if (n0q + r < W) lgp[(wv << 6) + n0q + r] = pl[r];
      }
    }
    __syncthreads();

    // ---- phase B: softmax + prefix sums, redundantly per wave ----
    {
      float lg = -3.0e38f;
      if (lane < W) {
        float s = selbv;
        #pragma unroll
        for (int dg = 0; dg < 8; ++dg) s += lgp[(dg << 6) + lane];
        lg = s;
      }
      float m = lg;
      m = dpp_max<0xB1>(m); m = dpp_max<0x4E>(m);
      m = dpp_max<0x124>(m); m = dpp_max<0x128>(m);
      m = fmaxf(m, __shfl_xor(m, 16, 64));
      m = fmaxf(m, __shfl_xor(m, 32, 64));
      const float e = (lane < W) ? __expf(lg - m) : 0.f;
      float t = e;
      t = dpp_add<0xB1, 0xF>(t); t = dpp_add<0x4E, 0xF>(t);
      t = dpp_add<0x124, 0xF>(t); t = dpp_add<0x128, 0xF>(t);
      t += __shfl_xor(t, 16, 64);
      t += __shfl_xor(t, 32, 64);
      const float p = e / t;
      // inclusive scan via DPP: shr1,2,4,8 then row_bcast15 (rows1,3), row_bcast31 (rows2,3)
      float cs = p;
      cs = dpp_add<0x111, 0xF>(cs);
      cs = dpp_add<0x112, 0xF>(cs);
      cs = dpp_add<0x114, 0xF>(cs);
      cs = dpp_add<0x118, 0xF>(cs);
      cs = dpp_add<0x142, 0xA>(cs);
      cs = dpp_add<0x143, 0xC>(cs);
      const float T = __shfl(cs, 63, 64);
      if (lane < W) {
        pS[lane]  = p;
        clS[lane] = T - cs;   // copy_left
        crS[lane] = cs - p;   // copy_right
      }
    }
    // (no barrier: each wave wrote its own redundant copy; same-value races benign)

    // ---- phase C: blend, own d-columns only ----
    #pragma unroll
    for (int mt = 0; mt < 4; ++mt) if (mt < NMT) {
      const int n0q = mt * 16 + quad * 4;
      const f32x4 pv  = *(const f32x4*)&pS[n0q];
      const f32x4 clv = *(const f32x4*)&clS[n0q];
      const f32x4 crv = *(const f32x4*)&crS[n0q];
      float oh[5], oc[5];
      #pragma unroll
      for (int r = 0; r < 5; ++r) {
        oh[r] = (float)hS[hOff(n0q + r, d)];
        oc[r] = cS[(n0q + r) * 132 + d];
      }
      #pragma unroll
      for (int r = 0; r < 4; ++r) {
        const int n = n0q + r;
        if (n < W) {
          const float nh = clv[r] * oh[r] + crv[r] * oh[r + 1] + pv[r] * ch[mt][r];
          const float nc = clv[r] * oc[r] + crv[r] * oc[r + 1] + pv[r] * cc[mt][r];
          hS[hOff(n, d)] = (f16)nh;
          cS[n * 132 + d] = nc;
        }
      }
    }
    __syncthreads();
  }

  // ---- write final state[0] = [h0 || c0] for the MLP kernel ----
  if (tid < 256) {
    const float v = (tid < 128) ? (float)hS[tid] : cS[tid - 128];  // hOff(0,f)=f
    fin[b * 256 + tid] = v;
  }
}

// ---- MLP head: 32 blocks x 1024 threads, 2 batch rows per block, f32 ----
__global__ __launch_bounds__(1024) void mlp_kernel(
    const float* __restrict__ fin,
    const float* __restrict__ w0, const float* __restrict__ b0,
    const float* __restrict__ w1, const float* __restrict__ b1,
    const float* __restrict__ cwt, const float* __restrict__ cbias,
    float* __restrict__ out)
{
  __shared__ float X[2][256];
  __shared__ float Z0[2][1024];
  __shared__ float Z1[2][1024];
  const int t  = threadIdx.x;
  const int r0 = blockIdx.x * 2;
  if (t < 512) { const int r = t >> 8, k = t & 255; X[r][k] = fin[(r0 + r) * 256 + k]; }
  __syncthreads();

  float a0 = b0[t], a1 = a0;
  #pragma unroll 4
  for (int k = 0; k < 256; ++k) {
    const float w = w0[k * 1024 + t];
    a0 = __builtin_fmaf(X[0][k], w, a0);
    a1 = __builtin_fmaf(X[1][k], w, a1);
  }
  Z0[0][t] = fmaxf(a0, 0.f); Z0[1][t] = fmaxf(a1, 0.f);
  __syncthreads();

  float c0 = b1[t], c1 = c0;
  #pragma unroll 4
  for (int k = 0; k < 1024; ++k) {
    const float w = w1[k * 1024 + t];
    c0 = __builtin_fmaf(Z0[0][k], w, c0);
    c1 = __builtin_fmaf(Z0[1][k], w, c1);
  }
  Z1[0][t] = fmaxf(c0, 0.f); Z1[1][t] = fmaxf(c1, 0.f);
  __syncthreads();

  const int wv = t >> 6, lane = t & 63;
  if (wv < 6) {                 // 6 (row, class) pairs
    const int r = wv / 3, cl = wv - 3 * r;
    float s = 0.f;
    #pragma unroll
    for (int i = 0; i < 16; ++i) {
      const int k = lane + (i << 6);
      s = __builtin_fmaf(Z1[r][k], cwt[k * 3 + cl], s);
    }
    #pragma unroll
    for (int off = 32; off >= 1; off >>= 1) s += __shfl_xor(s, off, 64);
    if (lane == 0) out[(r0 + r) * 3 + cl] = s + cbias[cl];
  }
}

extern "C" void kernel_launch(void* const* d_in, const int* in_sizes, int n_in,
                              void* d_out, int out_size, void* d_ws, size_t ws_size,
                              hipStream_t stream) {
  (void)in_sizes; (void)n_in; (void)out_size; (void)ws_size;
  f16*   wsB = (f16*)d_ws;                              // 409600 B
  float* fin = (float*)((char*)d_ws + 409600);          // 64*256*4 B

  prep_kernel<<<dim3(80), dim3(256), 0, stream>>>((const float*)d_in[3], wsB);
  pyramid_kernel<<<dim3(64), dim3(512), 0, stream>>>(
      (const int*)d_in[0],          // sentences
      (const float*)d_in[2],        // emb
      wsB,
      (const float*)d_in[4],        // comp_b
      (const float*)d_in[5],        // sel_w
      (const float*)d_in[6],        // sel_b
      fin);
  mlp_kernel<<<dim3(32), dim3(1024), 0, stream>>>(
      fin,
      (const float*)d_in[7],        // mlp_w0
      (const float*)d_in[8],        // mlp_b0
      (const float*)d_in[9],        // mlp_w1
      (const float*)d_in[10],       // mlp_b1
      (const float*)d_in[11],       // cls_w
      (const float*)d_in[12],       // cls_b
      (float*)d_out);
}

// Round 4
// 710.842 us; speedup vs baseline: 5.9873x; 1.2630x over previous
//
#include <hip/hip_runtime.h>

#define SEQ 64

typedef _Float16 f16;
typedef _Float16 f16x8 __attribute__((ext_vector_type(8)));
typedef _Float16 f16x2 __attribute__((ext_vector_type(2)));
typedef float f32x4 __attribute__((ext_vector_type(4)));

__device__ __forceinline__ float sig_(float x) { return 1.0f / (1.0f + __expf(-x)); }
__device__ __forceinline__ float tanh_(float x) { return 1.0f - 2.0f / (1.0f + __expf(2.0f * x)); }

template<int CTRL, int RMASK>
__device__ __forceinline__ float dpp_add(float x) {
  const int t = __builtin_amdgcn_update_dpp(0, __float_as_int(x), CTRL, RMASK, 0xF, true);
  return x + __int_as_float(t);
}
template<int CTRL>
__device__ __forceinline__ float dpp_max(float x) {
  const int t = __builtin_amdgcn_update_dpp(0, __float_as_int(x), CTRL, 0xF, 0xF, true);
  return fmaxf(x, __int_as_float(t));
}

// h state: node-major, 128 f16/row, XOR-swizzled in 8-f16 (16B) blocks
__device__ __forceinline__ int hOff(int n, int f) {
  return n * 128 + ((((f >> 3) ^ (n & 15)) << 3) | (f & 7));
}

// ---- prep: comp_W (256x640 fp32) -> f16 MFMA B-fragment order in ws ----
__global__ void prep_kernel(const float* __restrict__ cW, f16* __restrict__ wsB) {
  const int idx  = blockIdx.x * 256 + threadIdx.x;   // 0..20479
  const int kk   = idx / 2560;
  const int rem  = idx - kk * 2560;
  const int nt   = rem >> 6;
  const int lane = rem & 63;
  const int col  = nt * 16 + (lane & 15);
  const int kb   = kk * 32 + ((lane >> 4) << 3);
  f16x8 v;
  #pragma unroll
  for (int j = 0; j < 8; ++j) v[j] = (f16)cW[(kb + j) * 640 + col];
  ((f16x8*)wsB)[idx] = v;
}

__global__ __launch_bounds__(512, 2) void pyramid_kernel(
    const int*   __restrict__ sentences,
    const float* __restrict__ emb,
    const f16*   __restrict__ wsB,
    const float* __restrict__ cb, const float* __restrict__ selw, const float* __restrict__ selb,
    float* __restrict__ fin)
{
  __shared__ __align__(16) f16   hS[65 * 128];    // 16640 B
  __shared__ __align__(16) f16x8 Blds[5 * 512];   // 40960 B (B frags q=4, kk=3..7)
  __shared__ float lgp[8 * 64];                   // 2048 B
  __shared__ __align__(16) float pS[64], clS[64], crS[64];  // 768 B
  // total static LDS = 60416 B < 64 KB

  const int tid  = threadIdx.x;
  const int b    = blockIdx.x;
  const int wv   = tid >> 6;
  const int lane = tid & 63;
  const int quad = lane >> 4;
  const int l15  = lane & 15;
  const int d    = wv * 16 + l15;
  const f16x8* Bf = (const f16x8*)wsB;

  // ---- persistent B: 35 frags in regs (140 VGPR), 5 frag-sets in LDS ----
  f16x8 Breg[35];
  #pragma unroll
  for (int kk = 0; kk < 8; ++kk)
    #pragma unroll
    for (int q = 0; q < 4; ++q)
      Breg[kk * 4 + q] = Bf[((kk * 40 + q * 8 + wv) << 6) + lane];
  #pragma unroll
  for (int kk = 0; kk < 3; ++kk)
    Breg[32 + kk] = Bf[((kk * 40 + 32 + wv) << 6) + lane];
  #pragma unroll
  for (int s = 0; s < 5; ++s)
    Blds[s * 512 + (wv << 6) + lane] = Bf[(((s + 3) * 40 + 32 + wv) << 6) + lane];

  // ---- embedding: h-half -> LDS ----
  {
    const int s = tid >> 3, part = tid & 7;
    if (part < 4) {
      const int row = sentences[b * SEQ + s];
      const float4* er = (const float4*)(emb + (size_t)row * 256 + part * 32);
      #pragma unroll
      for (int i4 = 0; i4 < 8; ++i4) {
        const float4 v = er[i4];
        const int f = part * 32 + i4 * 4;
        hS[hOff(s, f + 0)] = (f16)v.x; hS[hOff(s, f + 1)] = (f16)v.y;
        hS[hOff(s, f + 2)] = (f16)v.z; hS[hOff(s, f + 3)] = (f16)v.w;
      }
    }
  }
  // ---- embedding: c-half -> owner registers ----
  float cReg[4][4];   // cReg[mt][r] = c[node mt*16+quad*4+r][d]
  #pragma unroll
  for (int mt = 0; mt < 4; ++mt)
    #pragma unroll
    for (int r = 0; r < 4; ++r) {
      const int n = mt * 16 + quad * 4 + r;
      const int row = sentences[b * SEQ + n];
      cReg[mt][r] = emb[(size_t)row * 256 + 128 + d];
    }
  if (tid < 128) hS[64 * 128 + tid] = (f16)0.f;   // guard row (node 64)
  __syncthreads();

  float bq[5];
  #pragma unroll
  for (int q = 0; q < 5; ++q) bq[q] = cb[q * 128 + d];
  const float swh = selw[d], swc = selw[128 + d], selbv = selb[0];

  // ---- pyramid: 63 sequential layers; zero global memory in the loop ----
  for (int W = 63; W >= 1; --W) {
    const int NMT = (W + 15) >> 4;
    f16x2 chP[4][2];     // comp_h, packed f16
    float ccR[4][4];     // comp_c, f32

    // ---- phase A: MFMA + gate epilogue, one mt at a time (acc reused) ----
    #pragma unroll
    for (int mt = 0; mt < 4; ++mt) if (mt < NMT) {
      f32x4 acc[5];
      #pragma unroll
      for (int q = 0; q < 5; ++q) acc[q] = (f32x4){bq[q], bq[q], bq[q], bq[q]};
      #pragma unroll
      for (int kk = 0; kk < 8; ++kk) {
        const int n   = mt * 16 + l15 + (kk >> 2);   // right half reads node n+1
        const int blk = (kk & 3) * 4 + quad;
        const f16x8 av = *(const f16x8*)&hS[n * 128 + ((blk ^ (n & 15)) << 3)];
        #pragma unroll
        for (int q = 0; q < 4; ++q)
          acc[q] = __builtin_amdgcn_mfma_f32_16x16x32_f16(av, Breg[kk * 4 + q], acc[q], 0, 0, 0);
        const f16x8 bo = (kk < 3) ? Breg[32 + kk]
                                  : Blds[(kk - 3) * 512 + (wv << 6) + lane];
        acc[4] = __builtin_amdgcn_mfma_f32_16x16x32_f16(av, bo, acc[4], 0, 0, 0);
      }
      // old-c neighbors (shuffles of OLD cReg; updates happen in phase C)
      const float cnq = __shfl_down(cReg[mt][0], 16, 64);                    // next quad
      const float cnm = (mt < 3) ? __shfl(cReg[mt + 1][0], l15, 64) : 0.f;   // next mt (from quad0)
      const float oc4 = (quad == 3) ? cnm : cnq;
      float pl[4];
      #pragma unroll
      for (int r = 0; r < 4; ++r) {
        const float ocl = cReg[mt][r];
        const float ocr = (r < 3) ? cReg[mt][r + 1] : oc4;
        const float c = sig_(acc[1][r]) * ocl + sig_(acc[2][r]) * ocr + sig_(acc[0][r]) * tanh_(acc[3][r]);
        const float h = sig_(acc[4][r]) * tanh_(c);
        ccR[mt][r] = c;
        chP[mt][r >> 1][r & 1] = (f16)h;
        pl[r] = __builtin_fmaf(h, swh, c * swc);
      }
      #pragma unroll
      for (int r = 0; r < 4; ++r) {    // reduce over 16 d-lanes via DPP
        float v = pl[r];
        v = dpp_add<0xB1, 0xF>(v);
        v = dpp_add<0x4E, 0xF>(v);
        v = dpp_add<0x124, 0xF>(v);
        v = dpp_add<0x128, 0xF>(v);
        pl[r] = v;
      }
      if (l15 == 0) {
        const int n0q = mt * 16 + quad * 4;
        #pragma unroll
        for (int r = 0; r < 4; ++r)
          if (n0q + r < W) lgp[(wv << 6) + n0q + r] = pl[r];
      }
    }
    __syncthreads();

    // ---- phase B: softmax + prefix sums, redundantly per wave ----
    {
      float lg = -3.0e38f;
      if (lane < W) {
        float s = selbv;
        #pragma unroll
        for (int dg = 0; dg < 8; ++dg) s += lgp[(dg << 6) + lane];
        lg = s;
      }
      float m = lg;
      m = dpp_max<0xB1>(m); m = dpp_max<0x4E>(m);
      m = dpp_max<0x124>(m); m = dpp_max<0x128>(m);
      m = fmaxf(m, __shfl_xor(m, 16, 64));
      m = fmaxf(m, __shfl_xor(m, 32, 64));
      const float e = (lane < W) ? __expf(lg - m) : 0.f;
      float t = e;
      t = dpp_add<0xB1, 0xF>(t); t = dpp_add<0x4E, 0xF>(t);
      t = dpp_add<0x124, 0xF>(t); t = dpp_add<0x128, 0xF>(t);
      t += __shfl_xor(t, 16, 64);
      t += __shfl_xor(t, 32, 64);
      const float p = e / t;
      float cs = p;                       // inclusive scan (DPP)
      cs = dpp_add<0x111, 0xF>(cs);
      cs = dpp_add<0x112, 0xF>(cs);
      cs = dpp_add<0x114, 0xF>(cs);
      cs = dpp_add<0x118, 0xF>(cs);
      cs = dpp_add<0x142, 0xA>(cs);
      cs = dpp_add<0x143, 0xC>(cs);
      const float T = __shfl(cs, 63, 64);
      if (lane < W) {
        pS[lane]  = p;
        clS[lane] = T - cs;
        crS[lane] = cs - p;
      }
    }
    // (no barrier: each wave wrote its own redundant copy)

    // ---- phase C: blend; h via LDS, c pure-register ----
    #pragma unroll
    for (int mt = 0; mt < 4; ++mt) if (mt < NMT) {
      const int n0q = mt * 16 + quad * 4;
      const f32x4 pv  = *(const f32x4*)&pS[n0q];
      const f32x4 clv = *(const f32x4*)&clS[n0q];
      const f32x4 crv = *(const f32x4*)&crS[n0q];
      float oh[5];
      #pragma unroll
      for (int r = 0; r < 5; ++r) oh[r] = (float)hS[hOff(n0q + r, d)];
      const float cnq = __shfl_down(cReg[mt][0], 16, 64);
      const float cnm = (mt < 3) ? __shfl(cReg[mt + 1][0], l15, 64) : 0.f;
      const float oc4 = (quad == 3) ? cnm : cnq;
      #pragma unroll
      for (int r = 0; r < 4; ++r) {
        const int n = n0q + r;
        const float ocl = cReg[mt][r];
        const float ocr = (r < 3) ? cReg[mt][r + 1] : oc4;
        if (n < W) {
          const float nh = clv[r] * oh[r] + crv[r] * oh[r + 1] + pv[r] * (float)chP[mt][r >> 1][r & 1];
          cReg[mt][r] = clv[r] * ocl + crv[r] * ocr + pv[r] * ccR[mt][r];
          hS[hOff(n, d)] = (f16)nh;
        }
      }
    }
    __syncthreads();
  }

  // ---- write final state[0] = [h0 || c0] ----
  if (tid < 128) fin[b * 256 + tid] = (float)hS[tid];     // hOff(0,f)=f
  if (quad == 0) fin[b * 256 + 128 + d] = cReg[0][0];     // node 0 owners
}

// ---- MLP head: col-split so weights are read once aggregate ----
__global__ __launch_bounds__(256) void z0_kernel(
    const float* __restrict__ fin, const float* __restrict__ w0,
    const float* __restrict__ b0, float* __restrict__ z0T)
{
  const int t = threadIdx.x;
  const int c = t & 15, rg = t >> 4;            // 16 cols x 16 row-groups(4)
  const int col = blockIdx.x * 16 + c;          // grid 64
  float a[4];
  const float bias = b0[col];
  #pragma unroll
  for (int r = 0; r < 4; ++r) a[r] = bias;
  #pragma unroll 8
  for (int k = 0; k < 256; ++k) {
    const float w = w0[k * 1024 + col];
    #pragma unroll
    for (int r = 0; r < 4; ++r)
      a[r] = __builtin_fmaf(fin[(rg * 4 + r) * 256 + k], w, a[r]);
  }
  #pragma unroll
  for (int r = 0; r < 4; ++r)
    z0T[col * 64 + rg * 4 + r] = fmaxf(a[r], 0.f);
}

__global__ __launch_bounds__(256) void z1_kernel(
    const float* __restrict__ z0T, const float* __restrict__ w1,
    const float* __restrict__ b1, float* __restrict__ z1T)
{
  const int t = threadIdx.x;
  const int c = t & 3, row = t >> 2;            // 4 cols x 64 rows
  const int col = blockIdx.x * 4 + c;           // grid 256
  float a = b1[col];
  #pragma unroll 8
  for (int k = 0; k < 1024; ++k)
    a = __builtin_fmaf(z0T[k * 64 + row], w1[k * 1024 + col], a);
  z1T[col * 64 + row] = fmaxf(a, 0.f);
}

__global__ __launch_bounds__(192) void out_kernel(
    const float* __restrict__ z1T, const float* __restrict__ cwt,
    const float* __restrict__ cbias, float* __restrict__ out)
{
  const int t = threadIdx.x;                    // 192 = 3 cls x 64 rows
  const int row = t & 63, cls = t >> 6;
  float a = cbias[cls];
  #pragma unroll 8
  for (int k = 0; k < 1024; ++k)
    a = __builtin_fmaf(z1T[k * 64 + row], cwt[k * 3 + cls], a);
  out[row * 3 + cls] = a;
}

extern "C" void kernel_launch(void* const* d_in, const int* in_sizes, int n_in,
                              void* d_out, int out_size, void* d_ws, size_t ws_size,
                              hipStream_t stream) {
  (void)in_sizes; (void)n_in; (void)out_size; (void)ws_size;
  f16*   wsB = (f16*)d_ws;                               // 409600 B
  float* fin = (float*)((char*)d_ws + 409600);           // 65536 B
  float* z0T = (float*)((char*)d_ws + 409600 + 65536);   // 262144 B
  float* z1T = (float*)((char*)d_ws + 409600 + 65536 + 262144);

  prep_kernel<<<dim3(80), dim3(256), 0, stream>>>((const float*)d_in[3], wsB);
  pyramid_kernel<<<dim3(64), dim3(512), 0, stream>>>(
      (const int*)d_in[0], (const float*)d_in[2], wsB,
      (const float*)d_in[4], (const float*)d_in[5], (const float*)d_in[6], fin);
  z0_kernel<<<dim3(64), dim3(256), 0, stream>>>(
      fin, (const float*)d_in[7], (const float*)d_in[8], z0T);
  z1_kernel<<<dim3(256), dim3(256), 0, stream>>>(
      z0T, (const float*)d_in[9], (const float*)d_in[10], z1T);
  out_kernel<<<dim3(1), dim3(192), 0, stream>>>(
      z1T, (const float*)d_in[11], (const float*)d_in[12], (float*)d_out);
}

// Round 5
// 705.800 us; speedup vs baseline: 6.0301x; 1.0071x over previous
//
#include <hip/hip_runtime.h>

#define SEQ 64

typedef _Float16 f16;
typedef _Float16 f16x8 __attribute__((ext_vector_type(8)));
typedef _Float16 f16x2 __attribute__((ext_vector_type(2)));
typedef float f32x4 __attribute__((ext_vector_type(4)));

__device__ __forceinline__ float sig_(float x) { return 1.0f / (1.0f + __expf(-x)); }
__device__ __forceinline__ float tanh_(float x) { return 1.0f - 2.0f / (1.0f + __expf(2.0f * x)); }

template<int CTRL, int RMASK>
__device__ __forceinline__ float dpp_add(float x) {
  const int t = __builtin_amdgcn_update_dpp(0, __float_as_int(x), CTRL, RMASK, 0xF, true);
  return x + __int_as_float(t);
}
template<int CTRL>
__device__ __forceinline__ float dpp_max(float x) {
  const int t = __builtin_amdgcn_update_dpp(0, __float_as_int(x), CTRL, 0xF, 0xF, true);
  return fmaxf(x, __int_as_float(t));
}

// h state: node-major, 128 f16/row, XOR-swizzled in 8-f16 (16B) blocks
__device__ __forceinline__ int hOff(int n, int f) {
  return n * 128 + ((((f >> 3) ^ (n & 15)) << 3) | (f & 7));
}

// ---- prep: comp_W (256x640 fp32) -> f16 MFMA B-fragment order in ws ----
__global__ void prep_kernel(const float* __restrict__ cW, f16* __restrict__ wsB) {
  const int idx  = blockIdx.x * 256 + threadIdx.x;   // 0..20479
  const int kk   = idx / 2560;
  const int rem  = idx - kk * 2560;
  const int nt   = rem >> 6;
  const int lane = rem & 63;
  const int col  = nt * 16 + (lane & 15);
  const int kb   = kk * 32 + ((lane >> 4) << 3);
  f16x8 v;
  #pragma unroll
  for (int j = 0; j < 8; ++j) v[j] = (f16)cW[(kb + j) * 640 + col];
  ((f16x8*)wsB)[idx] = v;
}

__global__ __launch_bounds__(512, 2) void pyramid_kernel(
    const int*   __restrict__ sentences,
    const float* __restrict__ emb,
    const f16*   __restrict__ wsB,
    const float* __restrict__ cb, const float* __restrict__ selw, const float* __restrict__ selb,
    float* __restrict__ fin)
{
  __shared__ __align__(16) f16   hS[65 * 128];    // 16640 B
  __shared__ __align__(16) f16x8 Blds[5 * 512];   // 40960 B (B frags q=4, kk=3..7)
  __shared__ float lgp[8 * 64];                   // 2048 B
  __shared__ __align__(16) float pS[64], clS[64], crS[64];  // 768 B

  const int tid  = threadIdx.x;
  const int b    = blockIdx.x;
  const int wv   = tid >> 6;
  const int lane = tid & 63;
  const int quad = lane >> 4;
  const int l15  = lane & 15;
  const int d    = wv * 16 + l15;
  const f16x8* Bf = (const f16x8*)wsB;

  // ---- persistent B: 35 frags in regs (140 VGPR), 5 frag-sets in LDS ----
  f16x8 Breg[35];
  #pragma unroll
  for (int kk = 0; kk < 8; ++kk)
    #pragma unroll
    for (int q = 0; q < 4; ++q)
      Breg[kk * 4 + q] = Bf[((kk * 40 + q * 8 + wv) << 6) + lane];
  #pragma unroll
  for (int kk = 0; kk < 3; ++kk)
    Breg[32 + kk] = Bf[((kk * 40 + 32 + wv) << 6) + lane];
  #pragma unroll
  for (int s = 0; s < 5; ++s)
    Blds[s * 512 + (wv << 6) + lane] = Bf[(((s + 3) * 40 + 32 + wv) << 6) + lane];

  // ---- embedding: h-half -> LDS ----
  {
    const int s = tid >> 3, part = tid & 7;
    if (part < 4) {
      const int row = sentences[b * SEQ + s];
      const float4* er = (const float4*)(emb + (size_t)row * 256 + part * 32);
      #pragma unroll
      for (int i4 = 0; i4 < 8; ++i4) {
        const float4 v = er[i4];
        const int f = part * 32 + i4 * 4;
        hS[hOff(s, f + 0)] = (f16)v.x; hS[hOff(s, f + 1)] = (f16)v.y;
        hS[hOff(s, f + 2)] = (f16)v.z; hS[hOff(s, f + 3)] = (f16)v.w;
      }
    }
  }
  // ---- embedding: c-half -> owner registers ----
  float cReg[4][4];   // cReg[mt][r] = c[node mt*16+quad*4+r][d]
  #pragma unroll
  for (int mt = 0; mt < 4; ++mt)
    #pragma unroll
    for (int r = 0; r < 4; ++r) {
      const int n = mt * 16 + quad * 4 + r;
      const int row = sentences[b * SEQ + n];
      cReg[mt][r] = emb[(size_t)row * 256 + 128 + d];
    }
  if (tid < 128) hS[64 * 128 + tid] = (f16)0.f;   // guard row (node 64)
  __syncthreads();

  // packed per-thread constants (f16 to cut register demand)
  f16x2 bqP[3];
  bqP[0][0] = (f16)cb[0 * 128 + d]; bqP[0][1] = (f16)cb[1 * 128 + d];
  bqP[1][0] = (f16)cb[2 * 128 + d]; bqP[1][1] = (f16)cb[3 * 128 + d];
  bqP[2][0] = (f16)cb[4 * 128 + d]; bqP[2][1] = (f16)0.f;
  f16x2 swP; swP[0] = (f16)selw[d]; swP[1] = (f16)selw[128 + d];
  const float selbv = selb[0];

  // ---- pyramid: 63 sequential layers; zero global memory in the loop ----
  for (int W = 63; W >= 1; --W) {
    const int NMT = (W + 15) >> 4;
    f16x2 chP[4][2];     // comp_h, packed f16
    f16x2 ccP[4][2];     // comp_c, packed f16

    // ---- phase A: MFMA + gate epilogue, one mt at a time (acc reused) ----
    #pragma unroll
    for (int mt = 0; mt < 4; ++mt) if (mt < NMT) {
      f32x4 acc[5];
      {
        const float b0v = (float)bqP[0][0], b1v = (float)bqP[0][1];
        const float b2v = (float)bqP[1][0], b3v = (float)bqP[1][1];
        const float b4v = (float)bqP[2][0];
        acc[0] = (f32x4){b0v, b0v, b0v, b0v};
        acc[1] = (f32x4){b1v, b1v, b1v, b1v};
        acc[2] = (f32x4){b2v, b2v, b2v, b2v};
        acc[3] = (f32x4){b3v, b3v, b3v, b3v};
        acc[4] = (f32x4){b4v, b4v, b4v, b4v};
      }
      #pragma unroll
      for (int kk = 0; kk < 8; ++kk) {
        const int n   = mt * 16 + l15 + (kk >> 2);   // right half reads node n+1
        const int blk = (kk & 3) * 4 + quad;
        const f16x8 av = *(const f16x8*)&hS[n * 128 + ((blk ^ (n & 15)) << 3)];
        #pragma unroll
        for (int q = 0; q < 4; ++q)
          acc[q] = __builtin_amdgcn_mfma_f32_16x16x32_f16(av, Breg[kk * 4 + q], acc[q], 0, 0, 0);
        const f16x8 bo = (kk < 3) ? Breg[32 + kk]
                                  : Blds[(kk - 3) * 512 + (wv << 6) + lane];
        acc[4] = __builtin_amdgcn_mfma_f32_16x16x32_f16(av, bo, acc[4], 0, 0, 0);
      }
      // old-c neighbors (shuffles of OLD cReg; updates happen in phase C)
      const float cnq = __shfl_down(cReg[mt][0], 16, 64);                    // next quad
      const float cnm = (mt < 3) ? __shfl(cReg[mt + 1][0], l15, 64) : 0.f;   // next mt
      const float oc4 = (quad == 3) ? cnm : cnq;
      const float swh = (float)swP[0], swc = (float)swP[1];
      #pragma unroll
      for (int r = 0; r < 4; ++r) {
        const float ocl = cReg[mt][r];
        const float ocr = (r < 3) ? cReg[mt][r + 1] : oc4;
        const float c = sig_(acc[1][r]) * ocl + sig_(acc[2][r]) * ocr + sig_(acc[0][r]) * tanh_(acc[3][r]);
        const float h = sig_(acc[4][r]) * tanh_(c);
        ccP[mt][r >> 1][r & 1] = (f16)c;
        chP[mt][r >> 1][r & 1] = (f16)h;
        // logit partial: reduce over 16 d-lanes via DPP, one r at a time
        float v = __builtin_fmaf(h, swh, c * swc);
        v = dpp_add<0xB1, 0xF>(v);
        v = dpp_add<0x4E, 0xF>(v);
        v = dpp_add<0x124, 0xF>(v);
        v = dpp_add<0x128, 0xF>(v);
        if (l15 == 0) {
          const int n = mt * 16 + quad * 4 + r;
          if (n < W) lgp[(wv << 6) + n] = v;
        }
      }
    }
    __syncthreads();

    // ---- phase B: softmax + prefix sums, redundantly per wave ----
    {
      float lg = -3.0e38f;
      if (lane < W) {
        float s = selbv;
        #pragma unroll
        for (int dg = 0; dg < 8; ++dg) s += lgp[(dg << 6) + lane];
        lg = s;
      }
      float m = lg;
      m = dpp_max<0xB1>(m); m = dpp_max<0x4E>(m);
      m = dpp_max<0x124>(m); m = dpp_max<0x128>(m);
      m = fmaxf(m, __shfl_xor(m, 16, 64));
      m = fmaxf(m, __shfl_xor(m, 32, 64));
      const float e = (lane < W) ? __expf(lg - m) : 0.f;
      float t = e;
      t = dpp_add<0xB1, 0xF>(t); t = dpp_add<0x4E, 0xF>(t);
      t = dpp_add<0x124, 0xF>(t); t = dpp_add<0x128, 0xF>(t);
      t += __shfl_xor(t, 16, 64);
      t += __shfl_xor(t, 32, 64);
      const float p = e / t;
      float cs = p;                       // inclusive scan (DPP)
      cs = dpp_add<0x111, 0xF>(cs);
      cs = dpp_add<0x112, 0xF>(cs);
      cs = dpp_add<0x114, 0xF>(cs);
      cs = dpp_add<0x118, 0xF>(cs);
      cs = dpp_add<0x142, 0xA>(cs);
      cs = dpp_add<0x143, 0xC>(cs);
      const float T = __shfl(cs, 63, 64);
      if (lane < W) {
        pS[lane]  = p;
        clS[lane] = T - cs;
        crS[lane] = cs - p;
      }
    }
    // (no barrier: each wave wrote its own redundant copy)

    // ---- phase C: blend; h via LDS, c pure-register ----
    #pragma unroll
    for (int mt = 0; mt < 4; ++mt) if (mt < NMT) {
      const int n0q = mt * 16 + quad * 4;
      const f32x4 pv  = *(const f32x4*)&pS[n0q];
      const f32x4 clv = *(const f32x4*)&clS[n0q];
      const f32x4 crv = *(const f32x4*)&crS[n0q];
      float oh[5];
      #pragma unroll
      for (int r = 0; r < 5; ++r) oh[r] = (float)hS[hOff(n0q + r, d)];
      const float cnq = __shfl_down(cReg[mt][0], 16, 64);
      const float cnm = (mt < 3) ? __shfl(cReg[mt + 1][0], l15, 64) : 0.f;
      const float oc4 = (quad == 3) ? cnm : cnq;
      #pragma unroll
      for (int r = 0; r < 4; ++r) {
        const int n = n0q + r;
        const float ocl = cReg[mt][r];
        const float ocr = (r < 3) ? cReg[mt][r + 1] : oc4;
        if (n < W) {
          const float nh = clv[r] * oh[r] + crv[r] * oh[r + 1] + pv[r] * (float)chP[mt][r >> 1][r & 1];
          cReg[mt][r] = clv[r] * ocl + crv[r] * ocr + pv[r] * (float)ccP[mt][r >> 1][r & 1];
          hS[hOff(n, d)] = (f16)nh;
        }
      }
    }
    __syncthreads();
  }

  // ---- write final state[0] = [h0 || c0] ----
  if (tid < 128) fin[b * 256 + tid] = (float)hS[tid];     // hOff(0,f)=f
  if (quad == 0) fin[b * 256 + 128 + d] = cReg[0][0];     // node 0 owners
}

// ---- fused MLP head: 64 blocks (one batch row) x 1024 threads ----
__global__ __launch_bounds__(1024) void mlp_kernel(
    const float* __restrict__ fin,
    const float* __restrict__ w0, const float* __restrict__ b0,
    const float* __restrict__ w1, const float* __restrict__ b1,
    const float* __restrict__ cwt, const float* __restrict__ cbias,
    float* __restrict__ out)
{
  __shared__ float X[256];
  __shared__ float Z0[1024];
  __shared__ float Z1[1024];
  const int t   = threadIdx.x;
  const int row = blockIdx.x;
  if (t < 256) X[t] = fin[row * 256 + t];
  __syncthreads();

  float a = b0[t];
  #pragma unroll 8
  for (int k = 0; k < 256; ++k)
    a = __builtin_fmaf(X[k], w0[k * 1024 + t], a);
  Z0[t] = fmaxf(a, 0.f);
  __syncthreads();

  float c = b1[t];
  #pragma unroll 8
  for (int k = 0; k < 1024; ++k)
    c = __builtin_fmaf(Z0[k], w1[k * 1024 + t], c);
  Z1[t] = fmaxf(c, 0.f);
  __syncthreads();

  const int wv = t >> 6, lane = t & 63;
  if (wv < 3) {            // wave = class
    float s = 0.f;
    #pragma unroll
    for (int i = 0; i < 16; ++i) {
      const int k = lane + (i << 6);
      s = __builtin_fmaf(Z1[k], cwt[k * 3 + wv], s);
    }
    #pragma unroll
    for (int off = 32; off >= 1; off >>= 1) s += __shfl_xor(s, off, 64);
    if (lane == 0) out[row * 3 + wv] = s + cbias[wv];
  }
}

extern "C" void kernel_launch(void* const* d_in, const int* in_sizes, int n_in,
                              void* d_out, int out_size, void* d_ws, size_t ws_size,
                              hipStream_t stream) {
  (void)in_sizes; (void)n_in; (void)out_size; (void)ws_size;
  f16*   wsB = (f16*)d_ws;                               // 409600 B
  float* fin = (float*)((char*)d_ws + 409600);           // 65536 B

  prep_kernel<<<dim3(80), dim3(256), 0, stream>>>((const float*)d_in[3], wsB);
  pyramid_kernel<<<dim3(64), dim3(512), 0, stream>>>(
      (const int*)d_in[0], (const float*)d_in[2], wsB,
      (const float*)d_in[4], (const float*)d_in[5], (const float*)d_in[6], fin);
  mlp_kernel<<<dim3(64), dim3(1024), 0, stream>>>(
      fin,
      (const float*)d_in[7], (const float*)d_in[8],
      (const float*)d_in[9], (const float*)d_in[10],
      (const float*)d_in[11], (const float*)d_in[12],
      (float*)d_out);
}